// Round 11
// baseline (196.724 us; speedup 1.0000x reference)
//
#include <hip/hip_runtime.h>
#include <hip/hip_bf16.h>

#define N 2048
#define NM1 2047
#define DT 256
#define ET 32
#define EC 128
#define NC 5
#define FS 80    // feats row stride (floats)
#define FD 69    // used feature cols
#define KC_ET 16 // k-chunks for ET GEMMs (chunk = 128)
#define KC_EC 16 // k-chunks for EC GEMM (chunk = 128)

typedef unsigned short u16;
typedef unsigned int u32;
typedef float f32x4 __attribute__((ext_vector_type(4)));
typedef __bf16 bf16x8 __attribute__((ext_vector_type(8)));

__device__ inline u16 bf16_rne(float x){
    unsigned int b = __float_as_uint(x);
    b += 0x7fffu + ((b >> 16) & 1u);
    return (u16)(b >> 16);
}
__device__ inline float bf16_to_f(u16 h){
    return __uint_as_float(((unsigned int)h) << 16);
}
__device__ inline f32x4 mfma16x16x32(bf16x8 a, bf16x8 b, f32x4 c){
    return __builtin_amdgcn_mfma_f32_16x16x32_bf16(a, b, c, 0, 0, 0);
}

// ==== k1: deg (0..511) + labels (512) + XW (513..1024) — r1/r7 verified ====
__global__ __launch_bounds__(256) void k_deg_label_xw(const float* __restrict__ tw,
                                                      const float* __restrict__ fw,
                                                      const int* __restrict__ labels,
                                                      const float* __restrict__ Xt,
                                                      const float* __restrict__ Wt,
                                                      const float* __restrict__ Xf,
                                                      const float* __restrict__ Wf,
                                                      float* __restrict__ degT,
                                                      float* __restrict__ degF,
                                                      float* __restrict__ cols,
                                                      float* __restrict__ Yt,
                                                      float* __restrict__ Yf){
    int b = blockIdx.x;
    int t = threadIdx.x;
    if (b < 512){
        int p = (b & 7)*256 + t;
        if (p >= NM1) return;
        int s0 = (b >> 3)*32;
        float lowT=0.f, highT=0.f, lowF=0.f, highF=0.f;
        #pragma unroll 8
        for (int r = 0; r < 32; ++r){
            int s = s0 + r;
            float vt = tw[(size_t)s*NM1 + p];
            float vf = fw[(size_t)s*NM1 + p];
            if (s <= p){ highT += vt; highF += vf; }
            else       { lowT  += vt; lowF  += vf; }
        }
        atomicAdd(&degT[p],   lowT);
        atomicAdd(&degF[p],   lowF);
        atomicAdd(&degT[p+1], highT);
        atomicAdd(&degF[p+1], highF);
        return;
    }
    if (b == 512){
        __shared__ float lc[NC];
        if (t < NC) lc[t] = 0.f;
        __syncthreads();
        for (int i = t; i < N; i += 256){
            int l = labels[i];
            if (l >= 0 && l < NC) lc[l] = 1.f;
        }
        __syncthreads();
        if (t < NC) cols[t] = lc[t];
        return;
    }
    int idx = b - 513;
    const float* X = (idx & 256) ? Xf : Xt;
    const float* W = (idx & 256) ? Wf : Wt;
    float*       Y = (idx & 256) ? Yf : Yt;
    __shared__ float Ws[DT*ET];
    __shared__ float Xs[8*DT];
    for (int j = t; j < DT*ET; j += 256) Ws[j] = W[j];
    int i0 = (idx & 255)*8;
    for (int j = t; j < 8*DT; j += 256) Xs[j] = X[(size_t)i0*DT + j];
    __syncthreads();
    int r = t >> 5, f = t & 31;
    const float* xr = Xs + r*DT;
    float acc = 0.f;
    #pragma unroll 8
    for (int d = 0; d < DT; ++d) acc += xr[d]*Ws[d*ET+f];
    Y[(size_t)(i0+r)*ET+f] = acc;
}

// ==== k2: split-K ET aggregation via split-bf16 MFMA — r7 body, i-tile 32 ====
// grid (64,16) = 1024 blocks -> 4 blocks/CU (LDS 34.8 KB). Waves 0-1 graph T,
// 2-3 graph F; wave-half wh picks the 16-row fragment. A-frags in registers
// from coalesced loads; Z staged once ([graph][plane][f][k]).
__global__ __launch_bounds__(256) void k_agg_et_m(const float* __restrict__ tw,
                                                  const float* __restrict__ fw,
                                                  const float* __restrict__ Yt,
                                                  const float* __restrict__ Yf,
                                                  const float* __restrict__ degT,
                                                  const float* __restrict__ degF,
                                                  float* __restrict__ Pt,
                                                  float* __restrict__ Pf){
    __shared__ u16 Zs[2][2][32][136];   // [graph][plane][f][k] 34816 B
    int t = threadIdx.x;
    int w = t >> 6, l = t & 63, lr = l & 15, lg = l >> 4;
    int g = w >> 1, wh = w & 1;
    int i0 = blockIdx.x*32;
    int kc = blockIdx.y;
    int k0 = kc*128;

    // stage Z for both graphs: thread t -> f = t>>3 (0..31), 16 consecutive k
    {
        int f = t >> 3;
        int kb16 = (t & 7)*16;
        #pragma unroll
        for (int gg = 0; gg < 2; ++gg){
            const float* Y   = gg ? Yf   : Yt;
            const float* deg = gg ? degF : degT;
            u16 h8[16], l8[16];
            #pragma unroll
            for (int j = 0; j < 16; ++j){
                int k = k0 + kb16 + j;
                float rd = rsqrtf(1.f + deg[k]);
                float v = rd * Y[(size_t)k*ET + f];
                u16 h = bf16_rne(v);
                h8[j] = h;
                l8[j] = bf16_rne(v - bf16_to_f(h));
            }
            uint4 pk;
            pk.x = (u32)h8[0] | ((u32)h8[1]<<16);
            pk.y = (u32)h8[2] | ((u32)h8[3]<<16);
            pk.z = (u32)h8[4] | ((u32)h8[5]<<16);
            pk.w = (u32)h8[6] | ((u32)h8[7]<<16);
            *(uint4*)&Zs[gg][0][f][kb16] = pk;
            pk.x = (u32)h8[8]  | ((u32)h8[9]<<16);
            pk.y = (u32)h8[10] | ((u32)h8[11]<<16);
            pk.z = (u32)h8[12] | ((u32)h8[13]<<16);
            pk.w = (u32)h8[14] | ((u32)h8[15]<<16);
            *(uint4*)&Zs[gg][0][f][kb16+8] = pk;
            pk.x = (u32)l8[0] | ((u32)l8[1]<<16);
            pk.y = (u32)l8[2] | ((u32)l8[3]<<16);
            pk.z = (u32)l8[4] | ((u32)l8[5]<<16);
            pk.w = (u32)l8[6] | ((u32)l8[7]<<16);
            *(uint4*)&Zs[gg][1][f][kb16] = pk;
            pk.x = (u32)l8[8]  | ((u32)l8[9]<<16);
            pk.y = (u32)l8[10] | ((u32)l8[11]<<16);
            pk.z = (u32)l8[12] | ((u32)l8[13]<<16);
            pk.w = (u32)l8[14] | ((u32)l8[15]<<16);
            *(uint4*)&Zs[gg][1][f][kb16+8] = pk;
        }
    }
    __syncthreads();

    const float* A = g ? fw : tw;
    f32x4 acc[2];
    acc[0] = (f32x4){0.f,0.f,0.f,0.f};
    acc[1] = (f32x4){0.f,0.f,0.f,0.f};

    for (int sub = 0; sub < 2; ++sub){
        int kb = k0 + sub*64;
        int row = i0 + wh*16 + lr;
        #pragma unroll
        for (int ks = 0; ks < 2; ++ks){
            int kbase = kb + ks*32 + lg*8;
            u16 ah[8], al[8];
            #pragma unroll
            for (int j = 0; j < 8; ++j){
                int k = kbase + j;
                float v = 0.f;
                if (row != k) v = A[(size_t)k*NM1 + row - (row > k ? 1 : 0)];
                u16 h = bf16_rne(v);
                ah[j] = h;
                al[j] = bf16_rne(v - bf16_to_f(h));
            }
            uint4 pa, pb;
            pa.x = (u32)ah[0] | ((u32)ah[1]<<16);
            pa.y = (u32)ah[2] | ((u32)ah[3]<<16);
            pa.z = (u32)ah[4] | ((u32)ah[5]<<16);
            pa.w = (u32)ah[6] | ((u32)ah[7]<<16);
            pb.x = (u32)al[0] | ((u32)al[1]<<16);
            pb.y = (u32)al[2] | ((u32)al[3]<<16);
            pb.z = (u32)al[4] | ((u32)al[5]<<16);
            pb.w = (u32)al[6] | ((u32)al[7]<<16);
            bf16x8 aH = *(bf16x8*)&pa;
            bf16x8 aL = *(bf16x8*)&pb;
            int koff = sub*64 + ks*32 + lg*8;
            #pragma unroll
            for (int ff = 0; ff < 2; ++ff){
                bf16x8 bH = *(const bf16x8*)&Zs[g][0][ff*16+lr][koff];
                bf16x8 bL = *(const bf16x8*)&Zs[g][1][ff*16+lr][koff];
                acc[ff] = mfma16x16x32(aH, bH, acc[ff]);
                acc[ff] = mfma16x16x32(aL, bH, acc[ff]);
                acc[ff] = mfma16x16x32(aH, bL, acc[ff]);
            }
        }
    }
    float* P = g ? Pf : Pt;
    #pragma unroll
    for (int ff = 0; ff < 2; ++ff)
        #pragma unroll
        for (int r = 0; r < 4; ++r){
            int gi = i0 + wh*16 + lg*4 + r;   // C/D: row=(lane>>4)*4+reg
            P[(size_t)kc*(N*ET) + (size_t)gi*ET + ff*16 + lr] = acc[ff][r];
        }
}

// ==== k3: reduce partials + self term + scale + bias + lrelu + onehot — r7 verified ====
__global__ __launch_bounds__(256) void k_feats_epi(const float* __restrict__ Pt,
                                                   const float* __restrict__ Pf,
                                                   const float* __restrict__ Yt,
                                                   const float* __restrict__ Yf,
                                                   const float* __restrict__ degT,
                                                   const float* __restrict__ degF,
                                                   const float* __restrict__ bt,
                                                   const float* __restrict__ bfv,
                                                   const float* __restrict__ cols,
                                                   const int* __restrict__ qsize,
                                                   float* __restrict__ feats){
    int idx = blockIdx.x*256 + threadIdx.x;   // over 2048*64
    int i = idx >> 6;
    int f = idx & 63;
    float s, rd, b;
    if (f < ET){
        rd = rsqrtf(1.f + degT[i]);
        s = rd*Yt[(size_t)i*ET + f];
        #pragma unroll
        for (int kc = 0; kc < KC_ET; ++kc) s += Pt[(size_t)kc*(N*ET) + (size_t)i*ET + f];
        b = bt[f];
    } else {
        int g = f - ET;
        rd = rsqrtf(1.f + degF[i]);
        s = rd*Yf[(size_t)i*ET + g];
        #pragma unroll
        for (int kc = 0; kc < KC_ET; ++kc) s += Pf[(size_t)kc*(N*ET) + (size_t)i*ET + g];
        b = bfv[g];
    }
    float v = rd*s + b;
    feats[(size_t)i*FS + f] = v > 0.f ? v : 0.01f*v;
    if (f < NC){
        int nsup = N - qsize[0];
        feats[(size_t)i*FS + 2*ET + f] = (i < nsup) ? cols[f] : 0.f;
    }
}

// ==== k4: merged dispatch — blocks <1024: build_aw; >=1024: featswc (unscaled) — r7 verified ====
__global__ __launch_bounds__(256) void k_aw_zc(const float* __restrict__ feats,
                                               const float* __restrict__ Wc,
                                               u16* __restrict__ Aw_hi,
                                               u16* __restrict__ Aw_lo,
                                               u16* __restrict__ ZcT_hi,
                                               u16* __restrict__ ZcT_lo,
                                               float* __restrict__ dsum){
    __shared__ __align__(16) char sm[37632];
    int t = threadIdx.x;
    int b = blockIdx.x;
    if (b < 1024){
        float* fiT = (float*)sm;        // [dim][row] 64*68
        float* fjT = fiT + 64*68;
        int i0 = (b & 31)*64, j0 = (b >> 5)*64;
        {
            int row = t >> 2;
            int cb  = (t & 3)*16;
            const float4* si = (const float4*)(feats + (size_t)(i0+row)*FS + cb);
            const float4* sj = (const float4*)(feats + (size_t)(j0+row)*FS + cb);
            #pragma unroll
            for (int s = 0; s < 4; ++s){
                float4 v = si[s];
                float4 w = sj[s];
                int c = cb + s*4;
                fiT[(c+0)*68+row]=v.x; fiT[(c+1)*68+row]=v.y; fiT[(c+2)*68+row]=v.z; fiT[(c+3)*68+row]=v.w;
                fjT[(c+0)*68+row]=w.x; fjT[(c+1)*68+row]=w.y; fjT[(c+2)*68+row]=w.z; fjT[(c+3)*68+row]=w.w;
            }
        }
        __syncthreads();
        int tx = t & 15, ty = t >> 4;
        float acc[4][4];
        #pragma unroll
        for (int u=0;u<4;++u)
            #pragma unroll
            for (int v=0;v<4;++v) acc[u][v]=0.f;
        for (int d = 0; d < 64; ++d){
            float4 a4 = *(const float4*)&fiT[d*68 + ty*4];
            float4 b4 = *(const float4*)&fjT[d*68 + tx*4];
            const float* ap = (const float*)&a4;
            const float* bp = (const float*)&b4;
            #pragma unroll
            for (int u = 0; u < 4; ++u)
                #pragma unroll
                for (int v = 0; v < 4; ++v)
                    acc[u][v] += fabsf(ap[u]-bp[v]);
        }
        #pragma unroll
        for (int u = 0; u < 4; ++u){
            int gi = i0 + ty*4 + u;
            float po[4];
            u16 hh[4], ll[4];
            #pragma unroll
            for (int v = 0; v < 4; ++v){
                int gj = j0 + tx*4 + v;
                float w = (gi==gj) ? 1.0f : 1.0f/(acc[u][v] + 1e-5f);
                po[v] = w;
                u16 h = bf16_rne(w);
                hh[v] = h;
                ll[v] = bf16_rne(w - bf16_to_f(h));
            }
            uint2 ph, pl;
            ph.x = (u32)hh[0] | ((u32)hh[1]<<16);
            ph.y = (u32)hh[2] | ((u32)hh[3]<<16);
            pl.x = (u32)ll[0] | ((u32)ll[1]<<16);
            pl.y = (u32)ll[2] | ((u32)ll[3]<<16);
            *(uint2*)&Aw_hi[(size_t)gi*N + j0 + tx*4] = ph;
            *(uint2*)&Aw_lo[(size_t)gi*N + j0 + tx*4] = pl;
            float rs = (po[0]+po[1]) + (po[2]+po[3]);
            rs += __shfl_xor(rs, 1);
            rs += __shfl_xor(rs, 2);
            rs += __shfl_xor(rs, 4);
            rs += __shfl_xor(rs, 8);
            if (tx == 0) atomicAdd(&dsum[gi], rs);
        }
        return;
    }
    // featswc (unscaled), idx 0..255
    {
        float* Wcs = (float*)sm;          // FD*EC
        float* fr  = Wcs + FD*EC;         // [8][72]
        int idx = b - 1024;
        int i0 = idx*8;
        for (int j = t; j < FD*EC; j += 256) Wcs[j] = Wc[j];
        for (int j = t; j < 8*FD; j += 256){
            int r = j / FD;
            int c = j - r*FD;
            fr[r*72 + c] = feats[(size_t)(i0+r)*FS + c];
        }
        __syncthreads();
        int f  = t & 127;
        int rh = t >> 7;                  // rows rh*4 .. rh*4+3
        u16 hh[4], ll[4];
        #pragma unroll
        for (int rr = 0; rr < 4; ++rr){
            int r = rh*4 + rr;
            float acc = 0.f;
            #pragma unroll
            for (int d = 0; d < FD; ++d) acc += fr[r*72+d]*Wcs[d*EC+f];
            u16 h = bf16_rne(acc);
            hh[rr] = h;
            ll[rr] = bf16_rne(acc - bf16_to_f(h));
        }
        uint2 ph, pl;
        ph.x = (u32)hh[0] | ((u32)hh[1]<<16);
        ph.y = (u32)hh[2] | ((u32)hh[3]<<16);
        pl.x = (u32)ll[0] | ((u32)ll[1]<<16);
        pl.y = (u32)ll[2] | ((u32)ll[3]<<16);
        *(uint2*)&ZcT_hi[(size_t)f*N + i0 + rh*4] = ph;
        *(uint2*)&ZcT_lo[(size_t)f*N + i0 + rh*4] = pl;
    }
}

// ==== k5: split-K EC GEMM — r7 body, f-tile split 128->64 for 4 blocks/CU ====
// grid (64,16): bx = (i-tile<<1)|fh. LDS 36.9 KB. A scaled by rsqrt(dsum[k])
// at stage (r7-verified); Z stages only this block's 64-f half.
__global__ __launch_bounds__(256) void k_agg_ec(const u16* __restrict__ Aw_hi,
                                                const u16* __restrict__ Aw_lo,
                                                const u16* __restrict__ ZcT_hi,
                                                const u16* __restrict__ ZcT_lo,
                                                const float* __restrict__ dsum,
                                                float* __restrict__ Pe){
    __shared__ u16 Ah[64*72];    // [i][k]
    __shared__ u16 Al[64*72];
    __shared__ u16 Zh[64*72];    // [f_local][k]
    __shared__ u16 Zl[64*72];
    int t = threadIdx.x;
    int w  = t >> 6;
    int l  = t & 63;
    int lr = l & 15;
    int lg = l >> 4;
    int i0 = (blockIdx.x >> 1)*64;
    int fh = blockIdx.x & 1;
    int kb0 = blockIdx.y*128;
    f32x4 acc[4];
    #pragma unroll
    for (int tt = 0; tt < 4; ++tt) acc[tt] = (f32x4){0.f, 0.f, 0.f, 0.f};

    for (int sub = 0; sub < 2; ++sub){
        int kbs = kb0 + sub*64;
        #pragma unroll
        for (int e = 0; e < 2; ++e){
            int id = t + e*256;
            int row = id >> 3, ch = (id & 7)*8;
            uint4 vh = *(const uint4*)&Aw_hi[(size_t)(i0+row)*N + kbs + ch];
            uint4 vl = *(const uint4*)&Aw_lo[(size_t)(i0+row)*N + kbs + ch];
            const u16* ph = (const u16*)&vh;
            const u16* pl = (const u16*)&vl;
            u16 nh[8], nl[8];
            #pragma unroll
            for (int j = 0; j < 8; ++j){
                float a = bf16_to_f(ph[j]) + bf16_to_f(pl[j]);
                float v = a * rsqrtf(dsum[kbs + ch + j]);
                u16 h = bf16_rne(v);
                nh[j] = h;
                nl[j] = bf16_rne(v - bf16_to_f(h));
            }
            uint4 oh, ol;
            oh.x = (u32)nh[0] | ((u32)nh[1]<<16);
            oh.y = (u32)nh[2] | ((u32)nh[3]<<16);
            oh.z = (u32)nh[4] | ((u32)nh[5]<<16);
            oh.w = (u32)nh[6] | ((u32)nh[7]<<16);
            ol.x = (u32)nl[0] | ((u32)nl[1]<<16);
            ol.y = (u32)nl[2] | ((u32)nl[3]<<16);
            ol.z = (u32)nl[4] | ((u32)nl[5]<<16);
            ol.w = (u32)nl[6] | ((u32)nl[7]<<16);
            *(uint4*)&Ah[row*72 + ch] = oh;
            *(uint4*)&Al[row*72 + ch] = ol;
        }
        #pragma unroll
        for (int e = 0; e < 2; ++e){
            int id = t + e*256;
            int row = id >> 3, ch = (id & 7)*8;   // row 0..63 -> global f = fh*64+row
            uint4 vh = *(const uint4*)&ZcT_hi[(size_t)(fh*64 + row)*N + kbs + ch];
            uint4 vl = *(const uint4*)&ZcT_lo[(size_t)(fh*64 + row)*N + kbs + ch];
            *(uint4*)&Zh[row*72 + ch] = vh;
            *(uint4*)&Zl[row*72 + ch] = vl;
        }
        __syncthreads();
        #pragma unroll
        for (int ks = 0; ks < 2; ++ks){
            int aoff = (w*16 + lr)*72 + ks*32 + lg*8;
            bf16x8 aH = *(const bf16x8*)&Ah[aoff];
            bf16x8 aL = *(const bf16x8*)&Al[aoff];
            #pragma unroll
            for (int tt = 0; tt < 4; ++tt){
                int zoff = (tt*16 + lr)*72 + ks*32 + lg*8;
                bf16x8 bH = *(const bf16x8*)&Zh[zoff];
                bf16x8 bL = *(const bf16x8*)&Zl[zoff];
                acc[tt] = mfma16x16x32(aH, bH, acc[tt]);
                acc[tt] = mfma16x16x32(aL, bH, acc[tt]);
                acc[tt] = mfma16x16x32(aH, bL, acc[tt]);
            }
        }
        __syncthreads();
    }
    #pragma unroll
    for (int tt = 0; tt < 4; ++tt){
        #pragma unroll
        for (int r = 0; r < 4; ++r){
            int gi = i0 + w*16 + lg*4 + r;        // C/D: row=(lane>>4)*4+reg
            Pe[(size_t)blockIdx.y*(N*EC) + (size_t)gi*EC + fh*64 + tt*16 + lr] = acc[tt][r];
        }
    }
}

// ==== k6: reduce Pe + scale + bias + lrelu -> out — r7 verified ====
__global__ __launch_bounds__(256) void k_embfinal(const float* __restrict__ Pe,
                                                  const float* __restrict__ dsum,
                                                  const float* __restrict__ bc,
                                                  const float* __restrict__ Wo,
                                                  const float* __restrict__ bo,
                                                  float* __restrict__ out){
    __shared__ float vs[2][EC];
    __shared__ float Wos[EC*NC];
    __shared__ float bos[NC];
    int t = threadIdx.x;
    for (int idx = t; idx < EC*NC; idx += 256) Wos[idx] = Wo[idx];
    if (t < NC) bos[t] = bo[t];
    int rr = t >> 7, f = t & 127;
    int i = blockIdx.x*2 + rr;
    size_t idx = (size_t)i*EC + f;
    float s = 0.f;
    #pragma unroll
    for (int kc = 0; kc < KC_EC; ++kc) s += Pe[(size_t)kc*(N*EC) + idx];
    float v = rsqrtf(dsum[i])*s + bc[f];
    vs[rr][f] = v > 0.f ? v : 0.01f*v;
    __syncthreads();
    if (t < 2*NC){
        int r = t / NC;
        int c = t - r*NC;
        float a = bos[c];
        #pragma unroll 8
        for (int f2 = 0; f2 < EC; ++f2) a += vs[r][f2]*Wos[f2*NC+c];
        out[(size_t)(blockIdx.x*2 + r)*NC + c] = a;
    }
}

extern "C" void kernel_launch(void* const* d_in, const int* in_sizes, int n_in,
                              void* d_out, int out_size, void* d_ws, size_t ws_size,
                              hipStream_t stream) {
    const float* time_features = (const float*)d_in[0];
    const float* tw            = (const float*)d_in[2];
    const float* freq_features = (const float*)d_in[3];
    const float* fw            = (const float*)d_in[4];
    const int*   labels        = (const int*)d_in[5];
    const int*   qsize         = (const int*)d_in[7];
    const float* Wt  = (const float*)d_in[8];
    const float* bt  = (const float*)d_in[9];
    const float* Wf  = (const float*)d_in[10];
    const float* bfv = (const float*)d_in[11];
    const float* Wc  = (const float*)d_in[12];
    const float* bc  = (const float*)d_in[13];
    const float* Wo  = (const float*)d_in[14];
    const float* bo  = (const float*)d_in[15];
    float* out = (float*)d_out;

    float* ws    = (float*)d_ws;
    float* degT  = ws;                         // N   (memset)
    float* degF  = degT + N;                   // N   (memset)
    float* dsum  = degF + N;                   // N   (memset)
    float* colsb = dsum + N;                   // 8
    float* Yt    = colsb + 8;                  // N*ET
    float* Yf    = Yt + (size_t)N*ET;          // N*ET
    float* feats = Yf + (size_t)N*ET;          // N*FS
    float* Zc    = feats + (size_t)N*FS;       // N*EC floats (2 bf16 planes)
    float* Aw    = Zc + (size_t)N*EC;          // N*N floats (2 bf16 planes)
    float* Pt    = Aw + (size_t)N*N;           // KC_ET*N*ET
    float* Pf    = Pt + (size_t)KC_ET*N*ET;    // KC_ET*N*ET
    float* Pe    = Pf + (size_t)KC_ET*N*ET;    // KC_EC*N*EC

    u16* ZcT_hi = (u16*)Zc;
    u16* ZcT_lo = ZcT_hi + (size_t)N*EC;
    u16* Aw_hi  = (u16*)Aw;
    u16* Aw_lo  = Aw_hi + (size_t)N*N;

    hipMemsetAsync(degT, 0, 3*N*sizeof(float), stream);
    k_deg_label_xw<<<1025, 256, 0, stream>>>(tw, fw, labels,
                                             time_features, Wt, freq_features, Wf,
                                             degT, degF, colsb, Yt, Yf);
    k_agg_et_m<<<dim3(N/32, KC_ET), 256, 0, stream>>>(tw, fw, Yt, Yf, degT, degF, Pt, Pf);
    k_feats_epi<<<(N*64)/256, 256, 0, stream>>>(Pt, Pf, Yt, Yf, degT, degF,
                                                bt, bfv, colsb, qsize, feats);
    k_aw_zc<<<1280, 256, 0, stream>>>(feats, Wc, Aw_hi, Aw_lo, ZcT_hi, ZcT_lo, dsum);
    k_agg_ec<<<dim3(64, KC_EC), 256, 0, stream>>>(Aw_hi, Aw_lo, ZcT_hi, ZcT_lo, dsum, Pe);
    k_embfinal<<<N/2, 256, 0, stream>>>(Pe, dsum, bc, Wo, bo, out);
}

// Round 12
// 192.682 us; speedup vs baseline: 1.0210x; 1.0210x over previous
//
#include <hip/hip_runtime.h>
#include <hip/hip_bf16.h>

#define N 2048
#define NM1 2047
#define DT 256
#define ET 32
#define EC 128
#define NC 5
#define FS 80    // feats row stride (floats)
#define FD 69    // used feature cols
#define KC_ET 16 // k-chunks for ET GEMMs (chunk = 128)
#define KC_EC 16 // k-chunks for EC GEMM (chunk = 128)

typedef unsigned short u16;
typedef unsigned int u32;
typedef float f32x4 __attribute__((ext_vector_type(4)));
typedef __bf16 bf16x8 __attribute__((ext_vector_type(8)));

__device__ inline u16 bf16_rne(float x){
    unsigned int b = __float_as_uint(x);
    b += 0x7fffu + ((b >> 16) & 1u);
    return (u16)(b >> 16);
}
__device__ inline float bf16_to_f(u16 h){
    return __uint_as_float(((unsigned int)h) << 16);
}
__device__ inline f32x4 mfma16x16x32(bf16x8 a, bf16x8 b, f32x4 c){
    return __builtin_amdgcn_mfma_f32_16x16x32_bf16(a, b, c, 0, 0, 0);
}

// ==== k1: deg (0..511) + labels (512) + XW (513..1024) — r1 verified ====
__global__ __launch_bounds__(256) void k_deg_label_xw(const float* __restrict__ tw,
                                                      const float* __restrict__ fw,
                                                      const int* __restrict__ labels,
                                                      const float* __restrict__ Xt,
                                                      const float* __restrict__ Wt,
                                                      const float* __restrict__ Xf,
                                                      const float* __restrict__ Wf,
                                                      float* __restrict__ degT,
                                                      float* __restrict__ degF,
                                                      float* __restrict__ cols,
                                                      float* __restrict__ Yt,
                                                      float* __restrict__ Yf){
    int b = blockIdx.x;
    int t = threadIdx.x;
    if (b < 512){
        int p = (b & 7)*256 + t;
        if (p >= NM1) return;
        int s0 = (b >> 3)*32;
        float lowT=0.f, highT=0.f, lowF=0.f, highF=0.f;
        #pragma unroll 8
        for (int r = 0; r < 32; ++r){
            int s = s0 + r;
            float vt = tw[(size_t)s*NM1 + p];
            float vf = fw[(size_t)s*NM1 + p];
            if (s <= p){ highT += vt; highF += vf; }
            else       { lowT  += vt; lowF  += vf; }
        }
        atomicAdd(&degT[p],   lowT);
        atomicAdd(&degF[p],   lowF);
        atomicAdd(&degT[p+1], highT);
        atomicAdd(&degF[p+1], highF);
        return;
    }
    if (b == 512){
        __shared__ float lc[NC];
        if (t < NC) lc[t] = 0.f;
        __syncthreads();
        for (int i = t; i < N; i += 256){
            int l = labels[i];
            if (l >= 0 && l < NC) lc[l] = 1.f;
        }
        __syncthreads();
        if (t < NC) cols[t] = lc[t];
        return;
    }
    int idx = b - 513;
    const float* X = (idx & 256) ? Xf : Xt;
    const float* W = (idx & 256) ? Wf : Wt;
    float*       Y = (idx & 256) ? Yf : Yt;
    __shared__ float Ws[DT*ET];
    __shared__ float Xs[8*DT];
    for (int j = t; j < DT*ET; j += 256) Ws[j] = W[j];
    int i0 = (idx & 255)*8;
    for (int j = t; j < 8*DT; j += 256) Xs[j] = X[(size_t)i0*DT + j];
    __syncthreads();
    int r = t >> 5, f = t & 31;
    const float* xr = Xs + r*DT;
    float acc = 0.f;
    #pragma unroll 8
    for (int d = 0; d < DT; ++d) acc += xr[d]*Ws[d*ET+f];
    Y[(size_t)(i0+r)*ET+f] = acc;
}

// ==== k2: split-K ET aggregation via split-bf16 MFMA ====
// grid (32,16): 64-row i-tiles x 128-k chunks. 4 waves: waves 0-1 graph T,
// 2-3 graph F; wave-half owns 32 rows. A-fragments built in registers from
// coalesced global loads (no LDS, no k-loop barriers); Z ([f][k], scaled)
// staged once per block. Fragment pattern + C/D mapping verified in r1 k6.
__global__ __launch_bounds__(256) void k_agg_et_m(const float* __restrict__ tw,
                                                  const float* __restrict__ fw,
                                                  const float* __restrict__ Yt,
                                                  const float* __restrict__ Yf,
                                                  const float* __restrict__ degT,
                                                  const float* __restrict__ degF,
                                                  float* __restrict__ Pt,
                                                  float* __restrict__ Pf){
    __shared__ u16 Zs[2][2][32][136];   // [graph][plane][f][k] 34816 B
    int t = threadIdx.x;
    int w = t >> 6, l = t & 63, lr = l & 15, lg = l >> 4;
    int g = w >> 1, wh = w & 1;
    int i0 = blockIdx.x*64;
    int kc = blockIdx.y;
    int k0 = kc*128;

    // stage Z for both graphs: thread t -> f = t>>3 (0..31), 16 consecutive k
    {
        int f = t >> 3;
        int kb16 = (t & 7)*16;
        #pragma unroll
        for (int gg = 0; gg < 2; ++gg){
            const float* Y   = gg ? Yf   : Yt;
            const float* deg = gg ? degF : degT;
            u16 h8[16], l8[16];
            #pragma unroll
            for (int j = 0; j < 16; ++j){
                int k = k0 + kb16 + j;
                float rd = rsqrtf(1.f + deg[k]);
                float v = rd * Y[(size_t)k*ET + f];
                u16 h = bf16_rne(v);
                h8[j] = h;
                l8[j] = bf16_rne(v - bf16_to_f(h));
            }
            uint4 pk;
            pk.x = (u32)h8[0] | ((u32)h8[1]<<16);
            pk.y = (u32)h8[2] | ((u32)h8[3]<<16);
            pk.z = (u32)h8[4] | ((u32)h8[5]<<16);
            pk.w = (u32)h8[6] | ((u32)h8[7]<<16);
            *(uint4*)&Zs[gg][0][f][kb16] = pk;
            pk.x = (u32)h8[8]  | ((u32)h8[9]<<16);
            pk.y = (u32)h8[10] | ((u32)h8[11]<<16);
            pk.z = (u32)h8[12] | ((u32)h8[13]<<16);
            pk.w = (u32)h8[14] | ((u32)h8[15]<<16);
            *(uint4*)&Zs[gg][0][f][kb16+8] = pk;
            pk.x = (u32)l8[0] | ((u32)l8[1]<<16);
            pk.y = (u32)l8[2] | ((u32)l8[3]<<16);
            pk.z = (u32)l8[4] | ((u32)l8[5]<<16);
            pk.w = (u32)l8[6] | ((u32)l8[7]<<16);
            *(uint4*)&Zs[gg][1][f][kb16] = pk;
            pk.x = (u32)l8[8]  | ((u32)l8[9]<<16);
            pk.y = (u32)l8[10] | ((u32)l8[11]<<16);
            pk.z = (u32)l8[12] | ((u32)l8[13]<<16);
            pk.w = (u32)l8[14] | ((u32)l8[15]<<16);
            *(uint4*)&Zs[gg][1][f][kb16+8] = pk;
        }
    }
    __syncthreads();

    const float* A = g ? fw : tw;
    f32x4 acc[2][2];
    #pragma unroll
    for (int fi = 0; fi < 2; ++fi)
        #pragma unroll
        for (int ff = 0; ff < 2; ++ff) acc[fi][ff] = (f32x4){0.f,0.f,0.f,0.f};

    for (int sub = 0; sub < 2; ++sub){
        int kb = k0 + sub*64;
        #pragma unroll
        for (int fi = 0; fi < 2; ++fi){
            int row = i0 + wh*32 + fi*16 + lr;
            #pragma unroll
            for (int ks = 0; ks < 2; ++ks){
                int kbase = kb + ks*32 + lg*8;
                u16 ah[8], al[8];
                #pragma unroll
                for (int j = 0; j < 8; ++j){
                    int k = kbase + j;
                    float v = 0.f;
                    if (row != k) v = A[(size_t)k*NM1 + row - (row > k ? 1 : 0)];
                    u16 h = bf16_rne(v);
                    ah[j] = h;
                    al[j] = bf16_rne(v - bf16_to_f(h));
                }
                uint4 pa, pb;
                pa.x = (u32)ah[0] | ((u32)ah[1]<<16);
                pa.y = (u32)ah[2] | ((u32)ah[3]<<16);
                pa.z = (u32)ah[4] | ((u32)ah[5]<<16);
                pa.w = (u32)ah[6] | ((u32)ah[7]<<16);
                pb.x = (u32)al[0] | ((u32)al[1]<<16);
                pb.y = (u32)al[2] | ((u32)al[3]<<16);
                pb.z = (u32)al[4] | ((u32)al[5]<<16);
                pb.w = (u32)al[6] | ((u32)al[7]<<16);
                bf16x8 aH = *(bf16x8*)&pa;
                bf16x8 aL = *(bf16x8*)&pb;
                int koff = sub*64 + ks*32 + lg*8;
                #pragma unroll
                for (int ff = 0; ff < 2; ++ff){
                    bf16x8 bH = *(const bf16x8*)&Zs[g][0][ff*16+lr][koff];
                    bf16x8 bL = *(const bf16x8*)&Zs[g][1][ff*16+lr][koff];
                    acc[fi][ff] = mfma16x16x32(aH, bH, acc[fi][ff]);
                    acc[fi][ff] = mfma16x16x32(aL, bH, acc[fi][ff]);
                    acc[fi][ff] = mfma16x16x32(aH, bL, acc[fi][ff]);
                }
            }
        }
    }
    float* P = g ? Pf : Pt;
    #pragma unroll
    for (int fi = 0; fi < 2; ++fi)
        #pragma unroll
        for (int ff = 0; ff < 2; ++ff)
            #pragma unroll
            for (int r = 0; r < 4; ++r){
                int gi = i0 + wh*32 + fi*16 + lg*4 + r;   // row=(lane>>4)*4+reg
                P[(size_t)kc*(N*ET) + (size_t)gi*ET + ff*16 + lr] = acc[fi][ff][r];
            }
}

// ==== k3: reduce partials + self term + scale + bias + lrelu + onehot — r1 verified ====
__global__ __launch_bounds__(256) void k_feats_epi(const float* __restrict__ Pt,
                                                   const float* __restrict__ Pf,
                                                   const float* __restrict__ Yt,
                                                   const float* __restrict__ Yf,
                                                   const float* __restrict__ degT,
                                                   const float* __restrict__ degF,
                                                   const float* __restrict__ bt,
                                                   const float* __restrict__ bfv,
                                                   const float* __restrict__ cols,
                                                   const int* __restrict__ qsize,
                                                   float* __restrict__ feats){
    int idx = blockIdx.x*256 + threadIdx.x;   // over 2048*64
    int i = idx >> 6;
    int f = idx & 63;
    float s, rd, b;
    if (f < ET){
        rd = rsqrtf(1.f + degT[i]);
        s = rd*Yt[(size_t)i*ET + f];
        #pragma unroll
        for (int kc = 0; kc < KC_ET; ++kc) s += Pt[(size_t)kc*(N*ET) + (size_t)i*ET + f];
        b = bt[f];
    } else {
        int g = f - ET;
        rd = rsqrtf(1.f + degF[i]);
        s = rd*Yf[(size_t)i*ET + g];
        #pragma unroll
        for (int kc = 0; kc < KC_ET; ++kc) s += Pf[(size_t)kc*(N*ET) + (size_t)i*ET + g];
        b = bfv[g];
    }
    float v = rd*s + b;
    feats[(size_t)i*FS + f] = v > 0.f ? v : 0.01f*v;
    if (f < NC){
        int nsup = N - qsize[0];
        feats[(size_t)i*FS + 2*ET + f] = (i < nsup) ? cols[f] : 0.f;
    }
}

// ==== k4: merged dispatch — blocks <1024: build_aw (r1 body); >=1024: featswc
// (UNSCALED: dis[k] moved to k_agg_ec A-staging). Both read only feats. ====
__global__ __launch_bounds__(256) void k_aw_zc(const float* __restrict__ feats,
                                               const float* __restrict__ Wc,
                                               u16* __restrict__ Aw_hi,
                                               u16* __restrict__ Aw_lo,
                                               u16* __restrict__ ZcT_hi,
                                               u16* __restrict__ ZcT_lo,
                                               float* __restrict__ dsum){
    __shared__ __align__(16) char sm[37632];
    int t = threadIdx.x;
    int b = blockIdx.x;
    if (b < 1024){
        float* fiT = (float*)sm;        // [dim][row] 64*68
        float* fjT = fiT + 64*68;
        int i0 = (b & 31)*64, j0 = (b >> 5)*64;
        {
            int row = t >> 2;
            int cb  = (t & 3)*16;
            const float4* si = (const float4*)(feats + (size_t)(i0+row)*FS + cb);
            const float4* sj = (const float4*)(feats + (size_t)(j0+row)*FS + cb);
            #pragma unroll
            for (int s = 0; s < 4; ++s){
                float4 v = si[s];
                float4 w = sj[s];
                int c = cb + s*4;
                fiT[(c+0)*68+row]=v.x; fiT[(c+1)*68+row]=v.y; fiT[(c+2)*68+row]=v.z; fiT[(c+3)*68+row]=v.w;
                fjT[(c+0)*68+row]=w.x; fjT[(c+1)*68+row]=w.y; fjT[(c+2)*68+row]=w.z; fjT[(c+3)*68+row]=w.w;
            }
        }
        __syncthreads();
        int tx = t & 15, ty = t >> 4;
        float acc[4][4];
        #pragma unroll
        for (int u=0;u<4;++u)
            #pragma unroll
            for (int v=0;v<4;++v) acc[u][v]=0.f;
        for (int d = 0; d < 64; ++d){
            float4 a4 = *(const float4*)&fiT[d*68 + ty*4];
            float4 b4 = *(const float4*)&fjT[d*68 + tx*4];
            const float* ap = (const float*)&a4;
            const float* bp = (const float*)&b4;
            #pragma unroll
            for (int u = 0; u < 4; ++u)
                #pragma unroll
                for (int v = 0; v < 4; ++v)
                    acc[u][v] += fabsf(ap[u]-bp[v]);
        }
        #pragma unroll
        for (int u = 0; u < 4; ++u){
            int gi = i0 + ty*4 + u;
            float po[4];
            u16 hh[4], ll[4];
            #pragma unroll
            for (int v = 0; v < 4; ++v){
                int gj = j0 + tx*4 + v;
                float w = (gi==gj) ? 1.0f : 1.0f/(acc[u][v] + 1e-5f);
                po[v] = w;
                u16 h = bf16_rne(w);
                hh[v] = h;
                ll[v] = bf16_rne(w - bf16_to_f(h));
            }
            uint2 ph, pl;
            ph.x = (u32)hh[0] | ((u32)hh[1]<<16);
            ph.y = (u32)hh[2] | ((u32)hh[3]<<16);
            pl.x = (u32)ll[0] | ((u32)ll[1]<<16);
            pl.y = (u32)ll[2] | ((u32)ll[3]<<16);
            *(uint2*)&Aw_hi[(size_t)gi*N + j0 + tx*4] = ph;
            *(uint2*)&Aw_lo[(size_t)gi*N + j0 + tx*4] = pl;
            float rs = (po[0]+po[1]) + (po[2]+po[3]);
            rs += __shfl_xor(rs, 1);
            rs += __shfl_xor(rs, 2);
            rs += __shfl_xor(rs, 4);
            rs += __shfl_xor(rs, 8);
            if (tx == 0) atomicAdd(&dsum[gi], rs);
        }
        return;
    }
    // featswc (unscaled), idx 0..255
    {
        float* Wcs = (float*)sm;          // FD*EC
        float* fr  = Wcs + FD*EC;         // [8][72]
        int idx = b - 1024;
        int i0 = idx*8;
        for (int j = t; j < FD*EC; j += 256) Wcs[j] = Wc[j];
        for (int j = t; j < 8*FD; j += 256){
            int r = j / FD;
            int c = j - r*FD;
            fr[r*72 + c] = feats[(size_t)(i0+r)*FS + c];
        }
        __syncthreads();
        int f  = t & 127;
        int rh = t >> 7;                  // rows rh*4 .. rh*4+3
        u16 hh[4], ll[4];
        #pragma unroll
        for (int rr = 0; rr < 4; ++rr){
            int r = rh*4 + rr;
            float acc = 0.f;
            #pragma unroll
            for (int d = 0; d < FD; ++d) acc += fr[r*72+d]*Wcs[d*EC+f];
            u16 h = bf16_rne(acc);
            hh[rr] = h;
            ll[rr] = bf16_rne(acc - bf16_to_f(h));
        }
        uint2 ph, pl;
        ph.x = (u32)hh[0] | ((u32)hh[1]<<16);
        ph.y = (u32)hh[2] | ((u32)hh[3]<<16);
        pl.x = (u32)ll[0] | ((u32)ll[1]<<16);
        pl.y = (u32)ll[2] | ((u32)ll[3]<<16);
        *(uint2*)&ZcT_hi[(size_t)f*N + i0 + rh*4] = ph;
        *(uint2*)&ZcT_lo[(size_t)f*N + i0 + rh*4] = pl;
    }
}

// ==== k5: split-K EC GEMM (r1-verified body); A scaled by rsqrt(dsum[k]) at stage ====
__global__ __launch_bounds__(256) void k_agg_ec(const u16* __restrict__ Aw_hi,
                                                const u16* __restrict__ Aw_lo,
                                                const u16* __restrict__ ZcT_hi,
                                                const u16* __restrict__ ZcT_lo,
                                                const float* __restrict__ dsum,
                                                float* __restrict__ Pe){
    __shared__ u16 Ah[64*72];    // [i][k]
    __shared__ u16 Al[64*72];
    __shared__ u16 Zh[128*72];   // [f][k]
    __shared__ u16 Zl[128*72];
    int t = threadIdx.x;
    int w  = t >> 6;
    int l  = t & 63;
    int lr = l & 15;
    int lg = l >> 4;
    int i0 = blockIdx.x*64;
    int kb0 = blockIdx.y*128;
    f32x4 acc[8];
    #pragma unroll
    for (int tt = 0; tt < 8; ++tt) acc[tt] = (f32x4){0.f, 0.f, 0.f, 0.f};

    for (int sub = 0; sub < 2; ++sub){
        int kbs = kb0 + sub*64;
        #pragma unroll
        for (int e = 0; e < 2; ++e){
            int id = t + e*256;
            int row = id >> 3, ch = (id & 7)*8;
            uint4 vh = *(const uint4*)&Aw_hi[(size_t)(i0+row)*N + kbs + ch];
            uint4 vl = *(const uint4*)&Aw_lo[(size_t)(i0+row)*N + kbs + ch];
            // apply dis[k] = rsqrt(dsum[k]): recombine, scale, resplit
            const u16* ph = (const u16*)&vh;
            const u16* pl = (const u16*)&vl;
            u16 nh[8], nl[8];
            #pragma unroll
            for (int j = 0; j < 8; ++j){
                float a = bf16_to_f(ph[j]) + bf16_to_f(pl[j]);
                float v = a * rsqrtf(dsum[kbs + ch + j]);
                u16 h = bf16_rne(v);
                nh[j] = h;
                nl[j] = bf16_rne(v - bf16_to_f(h));
            }
            uint4 oh, ol;
            oh.x = (u32)nh[0] | ((u32)nh[1]<<16);
            oh.y = (u32)nh[2] | ((u32)nh[3]<<16);
            oh.z = (u32)nh[4] | ((u32)nh[5]<<16);
            oh.w = (u32)nh[6] | ((u32)nh[7]<<16);
            ol.x = (u32)nl[0] | ((u32)nl[1]<<16);
            ol.y = (u32)nl[2] | ((u32)nl[3]<<16);
            ol.z = (u32)nl[4] | ((u32)nl[5]<<16);
            ol.w = (u32)nl[6] | ((u32)nl[7]<<16);
            *(uint4*)&Ah[row*72 + ch] = oh;
            *(uint4*)&Al[row*72 + ch] = ol;
        }
        #pragma unroll
        for (int e = 0; e < 4; ++e){
            int id = t + e*256;
            int row = id >> 3, ch = (id & 7)*8;
            uint4 vh = *(const uint4*)&ZcT_hi[(size_t)row*N + kbs + ch];
            uint4 vl = *(const uint4*)&ZcT_lo[(size_t)row*N + kbs + ch];
            *(uint4*)&Zh[row*72 + ch] = vh;
            *(uint4*)&Zl[row*72 + ch] = vl;
        }
        __syncthreads();
        #pragma unroll
        for (int ks = 0; ks < 2; ++ks){
            int aoff = (w*16 + lr)*72 + ks*32 + lg*8;
            bf16x8 aH = *(const bf16x8*)&Ah[aoff];
            bf16x8 aL = *(const bf16x8*)&Al[aoff];
            #pragma unroll
            for (int tt = 0; tt < 8; ++tt){
                int zoff = (tt*16 + lr)*72 + ks*32 + lg*8;
                bf16x8 bH = *(const bf16x8*)&Zh[zoff];
                bf16x8 bL = *(const bf16x8*)&Zl[zoff];
                acc[tt] = mfma16x16x32(aH, bH, acc[tt]);
                acc[tt] = mfma16x16x32(aL, bH, acc[tt]);
                acc[tt] = mfma16x16x32(aH, bL, acc[tt]);
            }
        }
        __syncthreads();
    }
    #pragma unroll
    for (int tt = 0; tt < 8; ++tt){
        #pragma unroll
        for (int r = 0; r < 4; ++r){
            int gi = i0 + w*16 + lg*4 + r;        // C/D: row=(lane>>4)*4+reg
            Pe[(size_t)blockIdx.y*(N*EC) + (size_t)gi*EC + tt*16 + lr] = acc[tt][r];
        }
    }
}

// ==== k6: reduce Pe + scale + bias + lrelu -> out — r1 verified ====
__global__ __launch_bounds__(256) void k_embfinal(const float* __restrict__ Pe,
                                                  const float* __restrict__ dsum,
                                                  const float* __restrict__ bc,
                                                  const float* __restrict__ Wo,
                                                  const float* __restrict__ bo,
                                                  float* __restrict__ out){
    __shared__ float vs[2][EC];
    __shared__ float Wos[EC*NC];
    __shared__ float bos[NC];
    int t = threadIdx.x;
    for (int idx = t; idx < EC*NC; idx += 256) Wos[idx] = Wo[idx];
    if (t < NC) bos[t] = bo[t];
    int rr = t >> 7, f = t & 127;
    int i = blockIdx.x*2 + rr;
    size_t idx = (size_t)i*EC + f;
    float s = 0.f;
    #pragma unroll
    for (int kc = 0; kc < KC_EC; ++kc) s += Pe[(size_t)kc*(N*EC) + idx];
    float v = rsqrtf(dsum[i])*s + bc[f];
    vs[rr][f] = v > 0.f ? v : 0.01f*v;
    __syncthreads();
    if (t < 2*NC){
        int r = t / NC;
        int c = t - r*NC;
        float a = bos[c];
        #pragma unroll 8
        for (int f2 = 0; f2 < EC; ++f2) a += vs[r][f2]*Wos[f2*NC+c];
        out[(size_t)(blockIdx.x*2 + r)*NC + c] = a;
    }
}

extern "C" void kernel_launch(void* const* d_in, const int* in_sizes, int n_in,
                              void* d_out, int out_size, void* d_ws, size_t ws_size,
                              hipStream_t stream) {
    const float* time_features = (const float*)d_in[0];
    const float* tw            = (const float*)d_in[2];
    const float* freq_features = (const float*)d_in[3];
    const float* fw            = (const float*)d_in[4];
    const int*   labels        = (const int*)d_in[5];
    const int*   qsize         = (const int*)d_in[7];
    const float* Wt  = (const float*)d_in[8];
    const float* bt  = (const float*)d_in[9];
    const float* Wf  = (const float*)d_in[10];
    const float* bfv = (const float*)d_in[11];
    const float* Wc  = (const float*)d_in[12];
    const float* bc  = (const float*)d_in[13];
    const float* Wo  = (const float*)d_in[14];
    const float* bo  = (const float*)d_in[15];
    float* out = (float*)d_out;

    float* ws    = (float*)d_ws;
    float* degT  = ws;                         // N   (memset)
    float* degF  = degT + N;                   // N   (memset)
    float* dsum  = degF + N;                   // N   (memset)
    float* colsb = dsum + N;                   // 8
    float* Yt    = colsb + 8;                  // N*ET
    float* Yf    = Yt + (size_t)N*ET;          // N*ET
    float* feats = Yf + (size_t)N*ET;          // N*FS
    float* Zc    = feats + (size_t)N*FS;       // N*EC floats (2 bf16 planes)
    float* Aw    = Zc + (size_t)N*EC;          // N*N floats (2 bf16 planes)
    float* Pt    = Aw + (size_t)N*N;           // KC_ET*N*ET
    float* Pf    = Pt + (size_t)KC_ET*N*ET;    // KC_ET*N*ET
    float* Pe    = Pf + (size_t)KC_ET*N*ET;    // KC_EC*N*EC

    u16* ZcT_hi = (u16*)Zc;
    u16* ZcT_lo = ZcT_hi + (size_t)N*EC;
    u16* Aw_hi  = (u16*)Aw;
    u16* Aw_lo  = Aw_hi + (size_t)N*N;

    hipMemsetAsync(degT, 0, 3*N*sizeof(float), stream);
    k_deg_label_xw<<<1025, 256, 0, stream>>>(tw, fw, labels,
                                             time_features, Wt, freq_features, Wf,
                                             degT, degF, colsb, Yt, Yf);
    k_agg_et_m<<<dim3(N/64, KC_ET), 256, 0, stream>>>(tw, fw, Yt, Yf, degT, degF, Pt, Pf);
    k_feats_epi<<<(N*64)/256, 256, 0, stream>>>(Pt, Pf, Yt, Yf, degT, degF,
                                                bt, bfv, colsb, qsize, feats);
    k_aw_zc<<<1280, 256, 0, stream>>>(feats, Wc, Aw_hi, Aw_lo, ZcT_hi, ZcT_lo, dsum);
    k_agg_ec<<<dim3(N/64, KC_EC), 256, 0, stream>>>(Aw_hi, Aw_lo, ZcT_hi, ZcT_lo, dsum, Pe);
    k_embfinal<<<N/2, 256, 0, stream>>>(Pe, dsum, bc, Wo, bo, out);
}